// Round 13
// baseline (273.274 us; speedup 1.0000x reference)
//
#include <hip/hip_runtime.h>
#include <hip/hip_fp16.h>

#define NNODES 100000
#define NEDGES 3200000
#define FEAT 32
#define NITER 5
#define NF (NNODES * FEAT)

#define EDGE_BLOCKS (NEDGES / 256)     // 12500, exact

// bucket partition
#define BUCK_SH 8
#define BUCK_SZ 256                    // dsts per bucket
#define NBK 391                        // ceil(100000/256)
#define CHUNKF 4096                    // edges per fill/hist block
#define NBF 782                        // 782*4096 = 3,203,072 >= NEDGES
#define NT (NBF * NBK)                 // 305,762 matrix elements
#define NTB 299                        // ceil(NT/1024)

// ---- pass A: packed payload + bucket id + masked-weight partials ----
// pay[e] = (src | dstl<<20, w_bits); bkt[e] = dst>>8 (0xFFFF if masked)
__global__ void ws_kernel(const int* __restrict__ edge_index,
                          const int* __restrict__ edge_mask,
                          const float* __restrict__ edge_scale,
                          const float* __restrict__ pert_mask,
                          const float* __restrict__ edge_weight,
                          int2* __restrict__ pay,
                          unsigned short* __restrict__ bkt,
                          float* __restrict__ S_part) {
    const int e = blockIdx.x * 256 + threadIdx.x;   // grid covers NEDGES exactly
    const int m = edge_mask[e];
    const float w = (edge_weight[e] * (1.0f - pert_mask[e]) + pert_mask[e]) * edge_scale[e];
    const int src = edge_index[e];
    const int dst = edge_index[NEDGES + e];
    pay[e] = make_int2(src | ((dst & (BUCK_SZ - 1)) << 20), __float_as_int(w));
    bkt[e] = m ? (unsigned short)(dst >> BUCK_SH) : (unsigned short)0xFFFFu;
    float ms = m ? 0.0f : w;
    __shared__ float s[256];
    s[threadIdx.x] = ms;
    __syncthreads();
    for (int off = 128; off; off >>= 1) {
        if (threadIdx.x < off) s[threadIdx.x] += s[threadIdx.x + off];
        __syncthreads();
    }
    if (threadIdx.x == 0) S_part[blockIdx.x] = s[0];
}

__global__ void sreduce_kernel(const float* __restrict__ S_part, float* __restrict__ S) {
    __shared__ float s[1024];
    float a = 0.0f;
    for (int i = threadIdx.x; i < EDGE_BLOCKS; i += 1024) a += S_part[i];
    s[threadIdx.x] = a;
    __syncthreads();
    for (int off = 512; off; off >>= 1) {
        if (threadIdx.x < off) s[threadIdx.x] += s[threadIdx.x + off];
        __syncthreads();
    }
    if (threadIdx.x == 0) *S = s[0];
}

// ---- per-(block,bucket) histogram matrix: M[b*NBK + k] ----
__global__ void histmat_kernel(const unsigned short* __restrict__ bkt, int* __restrict__ M) {
    __shared__ int h[NBK];
    const int b = blockIdx.x;
    for (int k = threadIdx.x; k < NBK; k += 256) h[k] = 0;
    __syncthreads();
    const int base = b * CHUNKF;
    for (int it = 0; it < CHUNKF / 256; ++it) {
        const int e = base + it * 256 + threadIdx.x;
        if (e < NEDGES) {
            const unsigned short k = bkt[e];
            if (k != 0xFFFFu) atomicAdd(&h[k], 1);
        }
    }
    __syncthreads();
    for (int k = threadIdx.x; k < NBK; k += 256) M[b * NBK + k] = h[k];
}

// ---- 3-stage exclusive scan over M in bucket-major (transposed) order ----
__global__ void tscan1_kernel(const int* __restrict__ M, int* __restrict__ tb) {
    __shared__ int s[1024];
    const int i = blockIdx.x * 1024 + threadIdx.x;
    int v = 0;
    if (i < NT) v = M[(i % NBF) * NBK + (i / NBF)];
    s[threadIdx.x] = v;
    __syncthreads();
    for (int off = 512; off; off >>= 1) {
        if (threadIdx.x < off) s[threadIdx.x] += s[threadIdx.x + off];
        __syncthreads();
    }
    if (threadIdx.x == 0) tb[blockIdx.x] = s[0];
}

__global__ void tscan2_kernel(const int* __restrict__ tb, int* __restrict__ tboff,
                              int* __restrict__ bucket_base) {
    __shared__ int s[512];
    const int tid = threadIdx.x;
    int v = (tid < NTB) ? tb[tid] : 0;
    s[tid] = v;
    __syncthreads();
    for (int off = 1; off < 512; off <<= 1) {
        int t = (tid >= off) ? s[tid - off] : 0;
        __syncthreads();
        s[tid] += t;
        __syncthreads();
    }
    if (tid < NTB) tboff[tid] = s[tid] - v;     // exclusive
    if (tid == 511) bucket_base[NBK] = s[511];  // total unmasked edges
}

__global__ void tscan3_kernel(const int* __restrict__ M, const int* __restrict__ tboff,
                              int* __restrict__ scanT, int* __restrict__ bucket_base) {
    __shared__ int s[1024];
    const int tid = threadIdx.x;
    const int i = blockIdx.x * 1024 + tid;
    int v = 0;
    if (i < NT) v = M[(i % NBF) * NBK + (i / NBF)];
    s[tid] = v;
    __syncthreads();
    for (int off = 1; off < 1024; off <<= 1) {
        int t = (tid >= off) ? s[tid - off] : 0;
        __syncthreads();
        s[tid] += t;
        __syncthreads();
    }
    if (i < NT) {
        const int excl = tboff[blockIdx.x] + s[tid] - v;
        scanT[i] = excl;
        if (i % NBF == 0) bucket_base[i / NBF] = excl;
    }
}

// ---- fill: scatter packed payload to matrix offsets; no global atomics ----
__global__ void fill782_kernel(const int2* __restrict__ pay,
                               const unsigned short* __restrict__ bkt,
                               const int* __restrict__ scanT,
                               int2* __restrict__ e8tmp) {
    __shared__ int off[NBK];
    const int b = blockIdx.x;
    for (int k = threadIdx.x; k < NBK; k += 256) off[k] = scanT[k * NBF + b];
    __syncthreads();
    const int base = b * CHUNKF;
    for (int it = 0; it < CHUNKF / 256; ++it) {
        const int e = base + it * 256 + threadIdx.x;
        if (e < NEDGES) {
            const unsigned short k = bkt[e];
            if (k != 0xFFFFu) {
                const int pos = atomicAdd(&off[k], 1);
                e8tmp[pos] = pay[e];
            }
        }
    }
}

// ---- bucket sort: one block per bucket; LDS counting sort by local dst ----
// emits final dst-sorted e8 (x = byte offset into 32B fp16 half-rows, src<<5) and row_ptr
__global__ void bsort_kernel(const int2* __restrict__ e8tmp,
                             const int* __restrict__ bucket_base,
                             int2* __restrict__ e8,
                             int* __restrict__ row_ptr) {
    __shared__ int h[BUCK_SZ];
    __shared__ int s[BUCK_SZ];
    __shared__ int woff[BUCK_SZ];
    const int k = blockIdx.x;
    const int tid = threadIdx.x;
    const int base0 = bucket_base[k];
    const int cnt = bucket_base[k + 1] - base0;
    h[tid] = 0;
    __syncthreads();
    for (int i = tid; i < cnt; i += 256) {
        const int dstl = e8tmp[base0 + i].x >> 20;   // bits 20..27 (src < 2^17)
        atomicAdd(&h[dstl], 1);
    }
    __syncthreads();
    s[tid] = h[tid];
    __syncthreads();
    for (int off = 1; off < BUCK_SZ; off <<= 1) {
        int t = (tid >= off) ? s[tid - off] : 0;
        __syncthreads();
        s[tid] += t;
        __syncthreads();
    }
    {
        const int excl = s[tid] - h[tid];
        const int d = k * BUCK_SZ + tid;
        if (d < NNODES) row_ptr[d] = base0 + excl;
        woff[tid] = excl;
    }
    if (k == NBK - 1 && tid == 0) row_ptr[NNODES] = bucket_base[NBK];
    __syncthreads();
    for (int i = tid; i < cnt; i += 256) {
        const int2 v = e8tmp[base0 + i];
        const int dstl = v.x >> 20;
        const int src = v.x & 0xFFFFF;
        const int pos = atomicAdd(&woff[dstl], 1);
        e8[base0 + pos] = make_int2(src << 5, v.y);   // byte offset into 32B half-rows
    }
}

// ---- initial fp32 -> fp16 conversion of x0, split-half layout [2][NNODES][16] ----
__global__ void cvt_kernel(const float* __restrict__ x, __half* __restrict__ xh) {
    const int i = blockIdx.x * 256 + threadIdx.x;   // over NF/4
    const float4 v = reinterpret_cast<const float4*>(x)[i];
    const int node = i >> 3;
    const int q = i & 7;           // quarter-row: feats [q*4, q*4+4)
    const int fh = q >> 2;
    const int part = q & 3;
    __half2 h01 = __floats2half2_rn(v.x, v.y);
    __half2 h23 = __floats2half2_rn(v.z, v.w);
    *reinterpret_cast<uint2*>((char*)xh + (size_t)fh * (NNODES * 32) + node * 32 + part * 8)
        = make_uint2(*(unsigned*)&h01, *(unsigned*)&h23);
}

// ---- gather V5: XCD-pinned feature-split, 4 node-halves/wave, pipelined e8 ----
// bid&7 = XCD: XCDs 0-3 -> feat half 0, 4-7 -> half 1 (per-XCD footprint 3.2 MB < 4 MB L2).
// e8 read via nontemporal load (no L2 alloc) so the streaming edge list does not
// evict the pinned xh half-array; next round's e8 prefetched before current xh use.
__global__ void gather_kernel(const __half* __restrict__ xh,
                              const int* __restrict__ row_ptr,
                              const int2* __restrict__ e8,
                              const float* __restrict__ S,
                              float* __restrict__ out,       // non-null only on last iter
                              __half* __restrict__ outh) {
    const int bid = blockIdx.x;
    const int r = bid & 7;
    const int fh = r >> 2;                        // feature half
    const int blk = (bid >> 3) * 4 + (r & 3);     // [0, 6252)
    if (blk >= 6250) return;                      // 6250*16 = 100000 exactly
    const int lane = threadIdx.x & 63;
    const int wid = threadIdx.x >> 6;
    const int nq   = lane >> 4;                   // node quarter 0..3
    const int slot = (lane >> 1) & 7;             // edge slot 0..7
    const int part = lane & 1;                    // 16B part of the 32B half-row
    const int node = blk * 16 + wid * 4 + nq;
    const int beg = row_ptr[node];
    const int end = row_ptr[node + 1];
    const char* xhc = (const char*)xh + (size_t)fh * (NNODES * 32);

    // early self-term load (independent; hides epilogue latency)
    const uint4 hx = *reinterpret_cast<const uint4*>(xhc + node * 32 + (part << 4));

    float a0=0.f,a1=0.f,a2=0.f,a3=0.f,a4=0.f,a5=0.f,a6=0.f,a7=0.f;
    const int em1c = (end - 1 > beg) ? (end - 1) : beg;   // safe clamp index
    int i = beg + slot;
    bool valid = (i < end);
    long long sw8 = __builtin_nontemporal_load(
        reinterpret_cast<const long long*>(e8 + (valid ? i : em1c)));
    while (__any(valid)) {
        const int inext = i + 8;
        const bool vnext = (inext < end);
        const bool anext = __any(vnext);
        long long swn8 = 0;
        if (anext) {   // wave-uniform branch; prefetch next round's e8
            swn8 = __builtin_nontemporal_load(
                reinterpret_cast<const long long*>(e8 + (vnext ? inext : em1c)));
        }
        const int sx = (int)(sw8 & 0xFFFFFFFFll);           // src byte offset
        const float w = valid ? __int_as_float((int)(sw8 >> 32)) : 0.0f;
        const uint4 hv = *reinterpret_cast<const uint4*>(
            xhc + (size_t)(unsigned)sx + (part << 4));
        float2 f;
        f = __half22float2(*(const __half2*)&hv.x); a0 = fmaf(w, f.x, a0); a1 = fmaf(w, f.y, a1);
        f = __half22float2(*(const __half2*)&hv.y); a2 = fmaf(w, f.x, a2); a3 = fmaf(w, f.y, a3);
        f = __half22float2(*(const __half2*)&hv.z); a4 = fmaf(w, f.x, a4); a5 = fmaf(w, f.y, a5);
        f = __half22float2(*(const __half2*)&hv.w); a6 = fmaf(w, f.x, a6); a7 = fmaf(w, f.y, a7);
        if (!anext) break;
        i = inext; valid = vnext; sw8 = swn8;
    }
    // reduce across the 8 edge slots (lane bits 1..3): xor offsets 2, 4, 8
    #pragma unroll
    for (int off = 2; off <= 8; off <<= 1) {
        a0 += __shfl_xor(a0, off); a1 += __shfl_xor(a1, off);
        a2 += __shfl_xor(a2, off); a3 += __shfl_xor(a3, off);
        a4 += __shfl_xor(a4, off); a5 += __shfl_xor(a5, off);
        a6 += __shfl_xor(a6, off); a7 += __shfl_xor(a7, off);
    }
    if ((lane & 14) == 0) {   // slot == 0 lanes: {nq, part}
        float2 f;
        f = __half22float2(*(const __half2*)&hx.x); const float x0f = f.x, x1f = f.y;
        f = __half22float2(*(const __half2*)&hx.y); const float x2f = f.x, x3f = f.y;
        f = __half22float2(*(const __half2*)&hx.z); const float x4f = f.x, x5f = f.y;
        f = __half22float2(*(const __half2*)&hx.w); const float x6f = f.x, x7f = f.y;
        if (node == 0) {   // masked-edge bulk contribution
            const float S0 = *S;
            a0 = fmaf(S0, x0f, a0); a1 = fmaf(S0, x1f, a1);
            a2 = fmaf(S0, x2f, a2); a3 = fmaf(S0, x3f, a3);
            a4 = fmaf(S0, x4f, a4); a5 = fmaf(S0, x5f, a5);
            a6 = fmaf(S0, x6f, a6); a7 = fmaf(S0, x7f, a7);
        }
        const float r0 = fminf(fmaxf(x0f + fminf(fmaxf(a0 - x0f, -1.f), 1.f), 0.f), 2.f);
        const float r1 = fminf(fmaxf(x1f + fminf(fmaxf(a1 - x1f, -1.f), 1.f), 0.f), 2.f);
        const float r2 = fminf(fmaxf(x2f + fminf(fmaxf(a2 - x2f, -1.f), 1.f), 0.f), 2.f);
        const float r3 = fminf(fmaxf(x3f + fminf(fmaxf(a3 - x3f, -1.f), 1.f), 0.f), 2.f);
        const float r4 = fminf(fmaxf(x4f + fminf(fmaxf(a4 - x4f, -1.f), 1.f), 0.f), 2.f);
        const float r5 = fminf(fmaxf(x5f + fminf(fmaxf(a5 - x5f, -1.f), 1.f), 0.f), 2.f);
        const float r6 = fminf(fmaxf(x6f + fminf(fmaxf(a6 - x6f, -1.f), 1.f), 0.f), 2.f);
        const float r7 = fminf(fmaxf(x7f + fminf(fmaxf(a7 - x7f, -1.f), 1.f), 0.f), 2.f);
        __half2 h0 = __floats2half2_rn(r0, r1);
        __half2 h1 = __floats2half2_rn(r2, r3);
        __half2 h2 = __floats2half2_rn(r4, r5);
        __half2 h3 = __floats2half2_rn(r6, r7);
        uint4 hh;
        hh.x = *(unsigned*)&h0; hh.y = *(unsigned*)&h1;
        hh.z = *(unsigned*)&h2; hh.w = *(unsigned*)&h3;
        *reinterpret_cast<uint4*>((char*)outh + (size_t)fh * (NNODES * 32)
                                  + node * 32 + (part << 4)) = hh;
        if (out) {
            float* op = out + node * FEAT + (fh << 4) + (part << 3);
            *reinterpret_cast<float4*>(op)     = make_float4(r0, r1, r2, r3);
            *reinterpret_cast<float4*>(op + 4) = make_float4(r4, r5, r6, r7);
        }
    }
}

extern "C" void kernel_launch(void* const* d_in, const int* in_sizes, int n_in,
                              void* d_out, int out_size, void* d_ws, size_t ws_size,
                              hipStream_t stream) {
    const float* x0         = (const float*)d_in[0];
    const int*   edge_index = (const int*)d_in[1];
    const int*   edge_mask  = (const int*)d_in[2];
    const float* edge_scale = (const float*)d_in[3];
    const float* pert_mask  = (const float*)d_in[4];
    const float* edge_weight= (const float*)d_in[5];
    float* xout = (float*)d_out;

    // ---- workspace layout (time-multiplexed; pay is 25.6 MB — R12's crash was
    //      sizing it 12.8 and overlapping bkt) ----
    // [0, 80K)       scalars / scan partials
    // [80K, 480K)    row_ptr
    // [1M, 2.25M)    M
    // [3M, 4.25M)    scanT                      (dead after fill782)
    // [5M, 18M)      e8tmp (13 MiB)             (dead after bsort)
    // [18M, 31M)     e8 (13 MiB)                (live all gathers)
    // [31M, 57M)     pay (25.6 MB)              (dead after fill782)
    //   -> xh0 [31M, 37.4M), xh1 [38M, 44.4M)   (written from cvt/gather, after fill782)
    // [57M, 63.5M)   bkt (6.4 MB)               (dead after fill782)
    char* ws = (char*)d_ws;
    float* S        = (float*)(ws);                          // 4 B
    float* S_part   = (float*)(ws + 1024);                   // 12500 floats
    int*   tb       = (int*)(ws + 64 * 1024);                // 299 ints
    int*   tboff    = (int*)(ws + 68 * 1024);                // 299 ints
    int*   bbase    = (int*)(ws + 72 * 1024);                // 392 ints
    int*   row_ptr  = (int*)(ws + 80 * 1024);                // 100001 ints
    int*   M        = (int*)(ws + 1  * 1024 * 1024);         // NT ints (1.22 MB)
    int*   scanT    = (int*)(ws + 3  * 1024 * 1024);         // NT ints (1.22 MB)
    int2*  e8tmp    = (int2*)(ws + 5  * 1024 * 1024);        // ~12.8 MB used
    int2*  e8       = (int2*)(ws + 18 * 1024 * 1024);        // ~12.8 MB used
    int2*  pay      = (int2*)(ws + 31 * 1024 * 1024);        // 25.6 MB
    unsigned short* bkt = (unsigned short*)(ws + 57 * 1024 * 1024);  // 6.4 MB
    __half* xh0     = (__half*)(ws + 31 * 1024 * 1024);      // 6.4 MB, aliases dead pay
    __half* xh1     = (__half*)(ws + 38 * 1024 * 1024);      // 6.4 MB, aliases dead pay

    ws_kernel<<<EDGE_BLOCKS, 256, 0, stream>>>(edge_index, edge_mask, edge_scale,
                                               pert_mask, edge_weight, pay, bkt, S_part);
    sreduce_kernel<<<1, 1024, 0, stream>>>(S_part, S);
    histmat_kernel<<<NBF, 256, 0, stream>>>(bkt, M);
    tscan1_kernel<<<NTB, 1024, 0, stream>>>(M, tb);
    tscan2_kernel<<<1, 512, 0, stream>>>(tb, tboff, bbase);
    tscan3_kernel<<<NTB, 1024, 0, stream>>>(M, tboff, scanT, bbase);
    fill782_kernel<<<NBF, 256, 0, stream>>>(pay, bkt, scanT, e8tmp);
    bsort_kernel<<<NBK, 256, 0, stream>>>(e8tmp, bbase, e8, row_ptr);
    cvt_kernel<<<NF / 4 / 256, 256, 0, stream>>>(x0, xh0);   // 3125 blocks, exact

    // 5 gather iterations entirely in fp16 ping-pong; fp32 out written on last iter only
    const int gblocks = 12504;   // 1563*8: both halves, 16 nodes/block, 4 tail blocks idle
    __half* xhb[2] = { xh0, xh1 };
    for (int it = 0; it < NITER; ++it) {
        gather_kernel<<<gblocks, 256, 0, stream>>>(xhb[it & 1], row_ptr, e8, S,
                                                   (it == NITER - 1) ? xout : nullptr,
                                                   xhb[(it + 1) & 1]);
    }
}

// Round 14
// 239.398 us; speedup vs baseline: 1.1415x; 1.1415x over previous
//
#include <hip/hip_runtime.h>
#include <hip/hip_fp16.h>

#define NNODES 100000
#define NEDGES 3200000
#define FEAT 32
#define NITER 5
#define NF (NNODES * FEAT)

#define EDGE_BLOCKS (NEDGES / 256)     // 12500, exact

// bucket partition
#define BUCK_SH 8
#define BUCK_SZ 256                    // dsts per bucket
#define NBK 391                        // ceil(100000/256)
#define CHUNKF 4096                    // edges per fill/hist block
#define NBF 782                        // 782*4096 = 3,203,072 >= NEDGES
#define NT (NBF * NBK)                 // 305,762 matrix elements
#define NTB 299                        // ceil(NT/1024)

// ---- pass A: packed payload + bucket id + masked-weight partials ----
// pay[e] = (src | dstl<<20, w_bits); bkt[e] = dst>>8 (0xFFFF if masked)
__global__ void ws_kernel(const int* __restrict__ edge_index,
                          const int* __restrict__ edge_mask,
                          const float* __restrict__ edge_scale,
                          const float* __restrict__ pert_mask,
                          const float* __restrict__ edge_weight,
                          int2* __restrict__ pay,
                          unsigned short* __restrict__ bkt,
                          float* __restrict__ S_part) {
    const int e = blockIdx.x * 256 + threadIdx.x;   // grid covers NEDGES exactly
    const int m = edge_mask[e];
    const float w = (edge_weight[e] * (1.0f - pert_mask[e]) + pert_mask[e]) * edge_scale[e];
    const int src = edge_index[e];
    const int dst = edge_index[NEDGES + e];
    pay[e] = make_int2(src | ((dst & (BUCK_SZ - 1)) << 20), __float_as_int(w));
    bkt[e] = m ? (unsigned short)(dst >> BUCK_SH) : (unsigned short)0xFFFFu;
    float ms = m ? 0.0f : w;
    __shared__ float s[256];
    s[threadIdx.x] = ms;
    __syncthreads();
    for (int off = 128; off; off >>= 1) {
        if (threadIdx.x < off) s[threadIdx.x] += s[threadIdx.x + off];
        __syncthreads();
    }
    if (threadIdx.x == 0) S_part[blockIdx.x] = s[0];
}

__global__ void sreduce_kernel(const float* __restrict__ S_part, float* __restrict__ S) {
    __shared__ float s[1024];
    float a = 0.0f;
    for (int i = threadIdx.x; i < EDGE_BLOCKS; i += 1024) a += S_part[i];
    s[threadIdx.x] = a;
    __syncthreads();
    for (int off = 512; off; off >>= 1) {
        if (threadIdx.x < off) s[threadIdx.x] += s[threadIdx.x + off];
        __syncthreads();
    }
    if (threadIdx.x == 0) *S = s[0];
}

// ---- per-(block,bucket) histogram matrix: M[b*NBK + k] ----
__global__ void histmat_kernel(const unsigned short* __restrict__ bkt, int* __restrict__ M) {
    __shared__ int h[NBK];
    const int b = blockIdx.x;
    for (int k = threadIdx.x; k < NBK; k += 256) h[k] = 0;
    __syncthreads();
    const int base = b * CHUNKF;
    for (int it = 0; it < CHUNKF / 256; ++it) {
        const int e = base + it * 256 + threadIdx.x;
        if (e < NEDGES) {
            const unsigned short k = bkt[e];
            if (k != 0xFFFFu) atomicAdd(&h[k], 1);
        }
    }
    __syncthreads();
    for (int k = threadIdx.x; k < NBK; k += 256) M[b * NBK + k] = h[k];
}

// ---- 3-stage exclusive scan over M in bucket-major (transposed) order ----
__global__ void tscan1_kernel(const int* __restrict__ M, int* __restrict__ tb) {
    __shared__ int s[1024];
    const int i = blockIdx.x * 1024 + threadIdx.x;
    int v = 0;
    if (i < NT) v = M[(i % NBF) * NBK + (i / NBF)];
    s[threadIdx.x] = v;
    __syncthreads();
    for (int off = 512; off; off >>= 1) {
        if (threadIdx.x < off) s[threadIdx.x] += s[threadIdx.x + off];
        __syncthreads();
    }
    if (threadIdx.x == 0) tb[blockIdx.x] = s[0];
}

__global__ void tscan2_kernel(const int* __restrict__ tb, int* __restrict__ tboff,
                              int* __restrict__ bucket_base) {
    __shared__ int s[512];
    const int tid = threadIdx.x;
    int v = (tid < NTB) ? tb[tid] : 0;
    s[tid] = v;
    __syncthreads();
    for (int off = 1; off < 512; off <<= 1) {
        int t = (tid >= off) ? s[tid - off] : 0;
        __syncthreads();
        s[tid] += t;
        __syncthreads();
    }
    if (tid < NTB) tboff[tid] = s[tid] - v;     // exclusive
    if (tid == 511) bucket_base[NBK] = s[511];  // total unmasked edges
}

__global__ void tscan3_kernel(const int* __restrict__ M, const int* __restrict__ tboff,
                              int* __restrict__ scanT, int* __restrict__ bucket_base) {
    __shared__ int s[1024];
    const int tid = threadIdx.x;
    const int i = blockIdx.x * 1024 + tid;
    int v = 0;
    if (i < NT) v = M[(i % NBF) * NBK + (i / NBF)];
    s[tid] = v;
    __syncthreads();
    for (int off = 1; off < 1024; off <<= 1) {
        int t = (tid >= off) ? s[tid - off] : 0;
        __syncthreads();
        s[tid] += t;
        __syncthreads();
    }
    if (i < NT) {
        const int excl = tboff[blockIdx.x] + s[tid] - v;
        scanT[i] = excl;
        if (i % NBF == 0) bucket_base[i / NBF] = excl;
    }
}

// ---- fill: scatter packed payload to matrix offsets; no global atomics ----
__global__ void fill782_kernel(const int2* __restrict__ pay,
                               const unsigned short* __restrict__ bkt,
                               const int* __restrict__ scanT,
                               int2* __restrict__ e8tmp) {
    __shared__ int off[NBK];
    const int b = blockIdx.x;
    for (int k = threadIdx.x; k < NBK; k += 256) off[k] = scanT[k * NBF + b];
    __syncthreads();
    const int base = b * CHUNKF;
    for (int it = 0; it < CHUNKF / 256; ++it) {
        const int e = base + it * 256 + threadIdx.x;
        if (e < NEDGES) {
            const unsigned short k = bkt[e];
            if (k != 0xFFFFu) {
                const int pos = atomicAdd(&off[k], 1);
                e8tmp[pos] = pay[e];
            }
        }
    }
}

// ---- bucket sort: one block per bucket; LDS counting sort by local dst ----
// emits final dst-sorted e8 (x = byte offset into 32B fp16 half-rows, src<<5) and row_ptr
__global__ void bsort_kernel(const int2* __restrict__ e8tmp,
                             const int* __restrict__ bucket_base,
                             int2* __restrict__ e8,
                             int* __restrict__ row_ptr) {
    __shared__ int h[BUCK_SZ];
    __shared__ int s[BUCK_SZ];
    __shared__ int woff[BUCK_SZ];
    const int k = blockIdx.x;
    const int tid = threadIdx.x;
    const int base0 = bucket_base[k];
    const int cnt = bucket_base[k + 1] - base0;
    h[tid] = 0;
    __syncthreads();
    for (int i = tid; i < cnt; i += 256) {
        const int dstl = e8tmp[base0 + i].x >> 20;   // bits 20..27 (src < 2^17)
        atomicAdd(&h[dstl], 1);
    }
    __syncthreads();
    s[tid] = h[tid];
    __syncthreads();
    for (int off = 1; off < BUCK_SZ; off <<= 1) {
        int t = (tid >= off) ? s[tid - off] : 0;
        __syncthreads();
        s[tid] += t;
        __syncthreads();
    }
    {
        const int excl = s[tid] - h[tid];
        const int d = k * BUCK_SZ + tid;
        if (d < NNODES) row_ptr[d] = base0 + excl;
        woff[tid] = excl;
    }
    if (k == NBK - 1 && tid == 0) row_ptr[NNODES] = bucket_base[NBK];
    __syncthreads();
    for (int i = tid; i < cnt; i += 256) {
        const int2 v = e8tmp[base0 + i];
        const int dstl = v.x >> 20;
        const int src = v.x & 0xFFFFF;
        const int pos = atomicAdd(&woff[dstl], 1);
        e8[base0 + pos] = make_int2(src << 5, v.y);   // byte offset into 32B half-rows
    }
}

// ---- initial fp32 -> fp16 conversion of x0, split-half layout [2][NNODES][16] ----
__global__ void cvt_kernel(const float* __restrict__ x, __half* __restrict__ xh) {
    const int i = blockIdx.x * 256 + threadIdx.x;   // over NF/4
    const float4 v = reinterpret_cast<const float4*>(x)[i];
    const int node = i >> 3;
    const int q = i & 7;           // quarter-row: feats [q*4, q*4+4)
    const int fh = q >> 2;
    const int part = q & 3;
    __half2 h01 = __floats2half2_rn(v.x, v.y);
    __half2 h23 = __floats2half2_rn(v.z, v.w);
    *reinterpret_cast<uint2*>((char*)xh + (size_t)fh * (NNODES * 32) + node * 32 + part * 8)
        = make_uint2(*(unsigned*)&h01, *(unsigned*)&h23);
}

// ---- gather V4 (restored from R11 — R13's nt-load/prefetch variant regressed) ----
// bid&7 = XCD: XCDs 0-3 -> feat half 0, 4-7 -> half 1 (per-XCD footprint 3.2 MB < 4 MB L2).
// lane = nq(2) | slot(3) | part(1): 4 nodes x 8 edge slots x 2x16B parts.
// After xor-reduce over slot bits, lane (nq,part) owns its 8 output feats directly.
__global__ void gather_kernel(const __half* __restrict__ xh,
                              const int* __restrict__ row_ptr,
                              const int2* __restrict__ e8,
                              const float* __restrict__ S,
                              float* __restrict__ out,       // non-null only on last iter
                              __half* __restrict__ outh) {
    const int bid = blockIdx.x;
    const int r = bid & 7;
    const int fh = r >> 2;                        // feature half
    const int blk = (bid >> 3) * 4 + (r & 3);     // [0, 6252)
    if (blk >= 6250) return;                      // 6250*16 = 100000 exactly
    const int lane = threadIdx.x & 63;
    const int wid = threadIdx.x >> 6;
    const int nq   = lane >> 4;                   // node quarter 0..3
    const int slot = (lane >> 1) & 7;             // edge slot 0..7
    const int part = lane & 1;                    // 16B part of the 32B half-row
    const int node = blk * 16 + wid * 4 + nq;
    const int beg = row_ptr[node];
    const int end = row_ptr[node + 1];
    const char* xhc = (const char*)xh + (size_t)fh * (NNODES * 32);

    float a0=0.f,a1=0.f,a2=0.f,a3=0.f,a4=0.f,a5=0.f,a6=0.f,a7=0.f;
    const int em1c = (end - 1 > beg) ? (end - 1) : beg;   // safe clamp index
    for (int i = beg + slot; __any(i < end); i += 8) {
        const bool valid = (i < end);
        const int2 sw = e8[valid ? i : em1c];
        const float w = valid ? __int_as_float(sw.y) : 0.0f;
        const uint4 hv = *reinterpret_cast<const uint4*>(
            xhc + (size_t)(unsigned)sw.x + (part << 4));
        float2 f;
        f = __half22float2(*(const __half2*)&hv.x); a0 = fmaf(w, f.x, a0); a1 = fmaf(w, f.y, a1);
        f = __half22float2(*(const __half2*)&hv.y); a2 = fmaf(w, f.x, a2); a3 = fmaf(w, f.y, a3);
        f = __half22float2(*(const __half2*)&hv.z); a4 = fmaf(w, f.x, a4); a5 = fmaf(w, f.y, a5);
        f = __half22float2(*(const __half2*)&hv.w); a6 = fmaf(w, f.x, a6); a7 = fmaf(w, f.y, a7);
    }
    // reduce across the 8 edge slots (lane bits 1..3): xor offsets 2, 4, 8
    #pragma unroll
    for (int off = 2; off <= 8; off <<= 1) {
        a0 += __shfl_xor(a0, off); a1 += __shfl_xor(a1, off);
        a2 += __shfl_xor(a2, off); a3 += __shfl_xor(a3, off);
        a4 += __shfl_xor(a4, off); a5 += __shfl_xor(a5, off);
        a6 += __shfl_xor(a6, off); a7 += __shfl_xor(a7, off);
    }
    if ((lane & 14) == 0) {   // slot == 0 lanes: {nq, part}
        // self term from fp16 (8 feats)
        const uint4 hx = *reinterpret_cast<const uint4*>(xhc + node * 32 + (part << 4));
        float2 f;
        f = __half22float2(*(const __half2*)&hx.x); const float x0f = f.x, x1f = f.y;
        f = __half22float2(*(const __half2*)&hx.y); const float x2f = f.x, x3f = f.y;
        f = __half22float2(*(const __half2*)&hx.z); const float x4f = f.x, x5f = f.y;
        f = __half22float2(*(const __half2*)&hx.w); const float x6f = f.x, x7f = f.y;
        if (node == 0) {   // masked-edge bulk contribution
            const float S0 = *S;
            a0 = fmaf(S0, x0f, a0); a1 = fmaf(S0, x1f, a1);
            a2 = fmaf(S0, x2f, a2); a3 = fmaf(S0, x3f, a3);
            a4 = fmaf(S0, x4f, a4); a5 = fmaf(S0, x5f, a5);
            a6 = fmaf(S0, x6f, a6); a7 = fmaf(S0, x7f, a7);
        }
        const float r0 = fminf(fmaxf(x0f + fminf(fmaxf(a0 - x0f, -1.f), 1.f), 0.f), 2.f);
        const float r1 = fminf(fmaxf(x1f + fminf(fmaxf(a1 - x1f, -1.f), 1.f), 0.f), 2.f);
        const float r2 = fminf(fmaxf(x2f + fminf(fmaxf(a2 - x2f, -1.f), 1.f), 0.f), 2.f);
        const float r3 = fminf(fmaxf(x3f + fminf(fmaxf(a3 - x3f, -1.f), 1.f), 0.f), 2.f);
        const float r4 = fminf(fmaxf(x4f + fminf(fmaxf(a4 - x4f, -1.f), 1.f), 0.f), 2.f);
        const float r5 = fminf(fmaxf(x5f + fminf(fmaxf(a5 - x5f, -1.f), 1.f), 0.f), 2.f);
        const float r6 = fminf(fmaxf(x6f + fminf(fmaxf(a6 - x6f, -1.f), 1.f), 0.f), 2.f);
        const float r7 = fminf(fmaxf(x7f + fminf(fmaxf(a7 - x7f, -1.f), 1.f), 0.f), 2.f);
        __half2 h0 = __floats2half2_rn(r0, r1);
        __half2 h1 = __floats2half2_rn(r2, r3);
        __half2 h2 = __floats2half2_rn(r4, r5);
        __half2 h3 = __floats2half2_rn(r6, r7);
        uint4 hh;
        hh.x = *(unsigned*)&h0; hh.y = *(unsigned*)&h1;
        hh.z = *(unsigned*)&h2; hh.w = *(unsigned*)&h3;
        *reinterpret_cast<uint4*>((char*)outh + (size_t)fh * (NNODES * 32)
                                  + node * 32 + (part << 4)) = hh;
        if (out) {
            float* op = out + node * FEAT + (fh << 4) + (part << 3);
            *reinterpret_cast<float4*>(op)     = make_float4(r0, r1, r2, r3);
            *reinterpret_cast<float4*>(op + 4) = make_float4(r4, r5, r6, r7);
        }
    }
}

extern "C" void kernel_launch(void* const* d_in, const int* in_sizes, int n_in,
                              void* d_out, int out_size, void* d_ws, size_t ws_size,
                              hipStream_t stream) {
    const float* x0         = (const float*)d_in[0];
    const int*   edge_index = (const int*)d_in[1];
    const int*   edge_mask  = (const int*)d_in[2];
    const float* edge_scale = (const float*)d_in[3];
    const float* pert_mask  = (const float*)d_in[4];
    const float* edge_weight= (const float*)d_in[5];
    float* xout = (float*)d_out;

    // ---- workspace layout (time-multiplexed; pay = 25.6 MB full size) ----
    // [0, 80K)       scalars / scan partials
    // [80K, 480K)    row_ptr
    // [1M, 2.25M)    M
    // [3M, 4.25M)    scanT                      (dead after fill782)
    // [5M, 18M)      e8tmp (13 MiB)             (dead after bsort)
    // [18M, 31M)     e8 (13 MiB)                (live all gathers)
    // [31M, 57M)     pay (25.6 MB)              (dead after fill782)
    //   -> xh0 [31M, 37.4M), xh1 [38M, 44.4M)   (written from cvt/gather, after fill782)
    // [57M, 63.5M)   bkt (6.4 MB)               (dead after fill782)
    char* ws = (char*)d_ws;
    float* S        = (float*)(ws);                          // 4 B
    float* S_part   = (float*)(ws + 1024);                   // 12500 floats
    int*   tb       = (int*)(ws + 64 * 1024);                // 299 ints
    int*   tboff    = (int*)(ws + 68 * 1024);                // 299 ints
    int*   bbase    = (int*)(ws + 72 * 1024);                // 392 ints
    int*   row_ptr  = (int*)(ws + 80 * 1024);                // 100001 ints
    int*   M        = (int*)(ws + 1  * 1024 * 1024);         // NT ints (1.22 MB)
    int*   scanT    = (int*)(ws + 3  * 1024 * 1024);         // NT ints (1.22 MB)
    int2*  e8tmp    = (int2*)(ws + 5  * 1024 * 1024);        // ~12.8 MB used
    int2*  e8       = (int2*)(ws + 18 * 1024 * 1024);        // ~12.8 MB used
    int2*  pay      = (int2*)(ws + 31 * 1024 * 1024);        // 25.6 MB
    unsigned short* bkt = (unsigned short*)(ws + 57 * 1024 * 1024);  // 6.4 MB
    __half* xh0     = (__half*)(ws + 31 * 1024 * 1024);      // 6.4 MB, aliases dead pay
    __half* xh1     = (__half*)(ws + 38 * 1024 * 1024);      // 6.4 MB, aliases dead pay

    ws_kernel<<<EDGE_BLOCKS, 256, 0, stream>>>(edge_index, edge_mask, edge_scale,
                                               pert_mask, edge_weight, pay, bkt, S_part);
    sreduce_kernel<<<1, 1024, 0, stream>>>(S_part, S);
    histmat_kernel<<<NBF, 256, 0, stream>>>(bkt, M);
    tscan1_kernel<<<NTB, 1024, 0, stream>>>(M, tb);
    tscan2_kernel<<<1, 512, 0, stream>>>(tb, tboff, bbase);
    tscan3_kernel<<<NTB, 1024, 0, stream>>>(M, tboff, scanT, bbase);
    fill782_kernel<<<NBF, 256, 0, stream>>>(pay, bkt, scanT, e8tmp);
    bsort_kernel<<<NBK, 256, 0, stream>>>(e8tmp, bbase, e8, row_ptr);
    cvt_kernel<<<NF / 4 / 256, 256, 0, stream>>>(x0, xh0);   // 3125 blocks, exact

    // 5 gather iterations entirely in fp16 ping-pong; fp32 out written on last iter only
    const int gblocks = 12504;   // 1563*8: both halves, 16 nodes/block, 4 tail blocks idle
    __half* xhb[2] = { xh0, xh1 };
    for (int it = 0; it < NITER; ++it) {
        gather_kernel<<<gblocks, 256, 0, stream>>>(xhb[it & 1], row_ptr, e8, S,
                                                   (it == NITER - 1) ? xout : nullptr,
                                                   xhb[(it + 1) & 1]);
    }
}

// Round 15
// 219.596 us; speedup vs baseline: 1.2444x; 1.0902x over previous
//
#include <hip/hip_runtime.h>
#include <hip/hip_fp16.h>

#define NNODES 100000
#define NEDGES 3200000
#define FEAT 32
#define NITER 5
#define NF (NNODES * FEAT)

// bucket partition
#define BUCK_SH 8
#define BUCK_SZ 256                    // dsts per bucket
#define NBK 391                        // ceil(100000/256)
#define CHUNKF 4096                    // edges per ws/fill block
#define NBF 782                        // 782*4096 = 3,203,072 >= NEDGES
#define NT (NBF * NBK)                 // 305,762 matrix elements
#define NTB 299                        // ceil(NT/1024)

// ---- pass A (fused): packed payload + bucket id + per-block histogram + masked-sum ----
// pay[e] = (src | dstl<<20, w_bits); bkt[e] = dst>>8 (0xFFFF if masked); M[b*NBK+k] = count
__global__ void ws_kernel(const int* __restrict__ edge_index,
                          const int* __restrict__ edge_mask,
                          const float* __restrict__ edge_scale,
                          const float* __restrict__ pert_mask,
                          const float* __restrict__ edge_weight,
                          int2* __restrict__ pay,
                          unsigned short* __restrict__ bkt,
                          int* __restrict__ M,
                          float* __restrict__ S_part) {
    __shared__ int h[NBK];
    __shared__ float sred[256];
    const int b = blockIdx.x;
    for (int k = threadIdx.x; k < NBK; k += 256) h[k] = 0;
    __syncthreads();
    const int base = b * CHUNKF;
    float ms = 0.0f;
    for (int it = 0; it < CHUNKF / 256; ++it) {
        const int e = base + it * 256 + threadIdx.x;
        if (e < NEDGES) {
            const int m = edge_mask[e];
            const float w = (edge_weight[e] * (1.0f - pert_mask[e]) + pert_mask[e]) * edge_scale[e];
            const int src = edge_index[e];
            const int dst = edge_index[NEDGES + e];
            pay[e] = make_int2(src | ((dst & (BUCK_SZ - 1)) << 20), __float_as_int(w));
            if (m) {
                bkt[e] = (unsigned short)(dst >> BUCK_SH);
                atomicAdd(&h[dst >> BUCK_SH], 1);
            } else {
                bkt[e] = (unsigned short)0xFFFFu;
                ms += w;
            }
        }
    }
    sred[threadIdx.x] = ms;
    __syncthreads();                      // also orders all h[] atomics before M write
    for (int off = 128; off; off >>= 1) {
        if (threadIdx.x < off) sred[threadIdx.x] += sred[threadIdx.x + off];
        __syncthreads();
    }
    if (threadIdx.x == 0) S_part[b] = sred[0];
    for (int k = threadIdx.x; k < NBK; k += 256) M[b * NBK + k] = h[k];
}

__global__ void sreduce_kernel(const float* __restrict__ S_part, float* __restrict__ S) {
    __shared__ float s[1024];
    float a = 0.0f;
    for (int i = threadIdx.x; i < NBF; i += 1024) a += S_part[i];
    s[threadIdx.x] = a;
    __syncthreads();
    for (int off = 512; off; off >>= 1) {
        if (threadIdx.x < off) s[threadIdx.x] += s[threadIdx.x + off];
        __syncthreads();
    }
    if (threadIdx.x == 0) *S = s[0];
}

// ---- 3-stage exclusive scan over M in bucket-major (transposed) order ----
__global__ void tscan1_kernel(const int* __restrict__ M, int* __restrict__ tb) {
    __shared__ int s[1024];
    const int i = blockIdx.x * 1024 + threadIdx.x;
    int v = 0;
    if (i < NT) v = M[(i % NBF) * NBK + (i / NBF)];
    s[threadIdx.x] = v;
    __syncthreads();
    for (int off = 512; off; off >>= 1) {
        if (threadIdx.x < off) s[threadIdx.x] += s[threadIdx.x + off];
        __syncthreads();
    }
    if (threadIdx.x == 0) tb[blockIdx.x] = s[0];
}

__global__ void tscan2_kernel(const int* __restrict__ tb, int* __restrict__ tboff,
                              int* __restrict__ bucket_base) {
    __shared__ int s[512];
    const int tid = threadIdx.x;
    int v = (tid < NTB) ? tb[tid] : 0;
    s[tid] = v;
    __syncthreads();
    for (int off = 1; off < 512; off <<= 1) {
        int t = (tid >= off) ? s[tid - off] : 0;
        __syncthreads();
        s[tid] += t;
        __syncthreads();
    }
    if (tid < NTB) tboff[tid] = s[tid] - v;     // exclusive
    if (tid == 511) bucket_base[NBK] = s[511];  // total unmasked edges
}

__global__ void tscan3_kernel(const int* __restrict__ M, const int* __restrict__ tboff,
                              int* __restrict__ scanT, int* __restrict__ bucket_base) {
    __shared__ int s[1024];
    const int tid = threadIdx.x;
    const int i = blockIdx.x * 1024 + tid;
    int v = 0;
    if (i < NT) v = M[(i % NBF) * NBK + (i / NBF)];
    s[tid] = v;
    __syncthreads();
    for (int off = 1; off < 1024; off <<= 1) {
        int t = (tid >= off) ? s[tid - off] : 0;
        __syncthreads();
        s[tid] += t;
        __syncthreads();
    }
    if (i < NT) {
        const int excl = tboff[blockIdx.x] + s[tid] - v;
        scanT[i] = excl;
        if (i % NBF == 0) bucket_base[i / NBF] = excl;
    }
}

// ---- fill: scatter packed payload to matrix offsets; no global atomics ----
__global__ void fill782_kernel(const int2* __restrict__ pay,
                               const unsigned short* __restrict__ bkt,
                               const int* __restrict__ scanT,
                               int2* __restrict__ e8tmp) {
    __shared__ int off[NBK];
    const int b = blockIdx.x;
    for (int k = threadIdx.x; k < NBK; k += 256) off[k] = scanT[k * NBF + b];
    __syncthreads();
    const int base = b * CHUNKF;
    for (int it = 0; it < CHUNKF / 256; ++it) {
        const int e = base + it * 256 + threadIdx.x;
        if (e < NEDGES) {
            const unsigned short k = bkt[e];
            if (k != 0xFFFFu) {
                const int pos = atomicAdd(&off[k], 1);
                e8tmp[pos] = pay[e];
            }
        }
    }
}

// ---- bucket sort: one block per bucket; LDS counting sort by local dst ----
// emits final dst-sorted PACKED e4 (src<<15 | fp16(w) sans sign) and row_ptr.
// w >= 0 always ((ew*(1-pm)+pm)*es, all operands in [0,1)) so the sign bit is free.
__global__ void bsort_kernel(const int2* __restrict__ e8tmp,
                             const int* __restrict__ bucket_base,
                             unsigned* __restrict__ e4,
                             int* __restrict__ row_ptr) {
    __shared__ int h[BUCK_SZ];
    __shared__ int s[BUCK_SZ];
    __shared__ int woff[BUCK_SZ];
    const int k = blockIdx.x;
    const int tid = threadIdx.x;
    const int base0 = bucket_base[k];
    const int cnt = bucket_base[k + 1] - base0;
    h[tid] = 0;
    __syncthreads();
    for (int i = tid; i < cnt; i += 256) {
        const int dstl = e8tmp[base0 + i].x >> 20;   // bits 20..27 (src < 2^17)
        atomicAdd(&h[dstl], 1);
    }
    __syncthreads();
    s[tid] = h[tid];
    __syncthreads();
    for (int off = 1; off < BUCK_SZ; off <<= 1) {
        int t = (tid >= off) ? s[tid - off] : 0;
        __syncthreads();
        s[tid] += t;
        __syncthreads();
    }
    {
        const int excl = s[tid] - h[tid];
        const int d = k * BUCK_SZ + tid;
        if (d < NNODES) row_ptr[d] = base0 + excl;
        woff[tid] = excl;
    }
    if (k == NBK - 1 && tid == 0) row_ptr[NNODES] = bucket_base[NBK];
    __syncthreads();
    for (int i = tid; i < cnt; i += 256) {
        const int2 v = e8tmp[base0 + i];
        const int dstl = v.x >> 20;
        const unsigned src = (unsigned)(v.x & 0xFFFFF);
        __half hw = __float2half_rn(__int_as_float(v.y));
        const unsigned h16 = (unsigned)(*reinterpret_cast<unsigned short*>(&hw)) & 0x7FFFu;
        const int pos = atomicAdd(&woff[dstl], 1);
        e4[base0 + pos] = (src << 15) | h16;
    }
}

// ---- initial fp32 -> fp16 conversion of x0, split-half layout [2][NNODES][16] ----
__global__ void cvt_kernel(const float* __restrict__ x, __half* __restrict__ xh) {
    const int i = blockIdx.x * 256 + threadIdx.x;   // over NF/4
    const float4 v = reinterpret_cast<const float4*>(x)[i];
    const int node = i >> 3;
    const int q = i & 7;           // quarter-row: feats [q*4, q*4+4)
    const int fh = q >> 2;
    const int part = q & 3;
    __half2 h01 = __floats2half2_rn(v.x, v.y);
    __half2 h23 = __floats2half2_rn(v.z, v.w);
    *reinterpret_cast<uint2*>((char*)xh + (size_t)fh * (NNODES * 32) + node * 32 + part * 8)
        = make_uint2(*(unsigned*)&h01, *(unsigned*)&h23);
}

// ---- gather V4 + packed 4B edges ----
// bid&7 = XCD: XCDs 0-3 -> feat half 0, 4-7 -> half 1 (per-XCD footprint 3.2 MB < 4 MB L2).
// lane = nq(2) | slot(3) | part(1): 4 nodes x 8 edge slots x 2x16B parts.
// e4 entry: src<<15 | fp16(w)[14:0]. Byte offset = (v>>10) & ~31; w = bits[14:0] as fp16.
__global__ void gather_kernel(const __half* __restrict__ xh,
                              const int* __restrict__ row_ptr,
                              const unsigned* __restrict__ e4,
                              const float* __restrict__ S,
                              float* __restrict__ out,       // non-null only on last iter
                              __half* __restrict__ outh) {
    const int bid = blockIdx.x;
    const int r = bid & 7;
    const int fh = r >> 2;                        // feature half
    const int blk = (bid >> 3) * 4 + (r & 3);     // [0, 6252)
    if (blk >= 6250) return;                      // 6250*16 = 100000 exactly
    const int lane = threadIdx.x & 63;
    const int wid = threadIdx.x >> 6;
    const int nq   = lane >> 4;                   // node quarter 0..3
    const int slot = (lane >> 1) & 7;             // edge slot 0..7
    const int part = lane & 1;                    // 16B part of the 32B half-row
    const int node = blk * 16 + wid * 4 + nq;
    const int beg = row_ptr[node];
    const int end = row_ptr[node + 1];
    const char* xhc = (const char*)xh + (size_t)fh * (NNODES * 32);

    float a0=0.f,a1=0.f,a2=0.f,a3=0.f,a4=0.f,a5=0.f,a6=0.f,a7=0.f;
    const int em1c = (end - 1 > beg) ? (end - 1) : beg;   // safe clamp index
    for (int i = beg + slot; __any(i < end); i += 8) {
        const bool valid = (i < end);
        const unsigned v = e4[valid ? i : em1c];
        unsigned short w16 = (unsigned short)(v & 0x7FFFu);
        const float wv = __half2float(*reinterpret_cast<const __half*>(&w16));
        const float w = valid ? wv : 0.0f;
        const uint4 hv = *reinterpret_cast<const uint4*>(
            xhc + (size_t)((v >> 10) & 0xFFFFE0u) + (part << 4));
        float2 f;
        f = __half22float2(*(const __half2*)&hv.x); a0 = fmaf(w, f.x, a0); a1 = fmaf(w, f.y, a1);
        f = __half22float2(*(const __half2*)&hv.y); a2 = fmaf(w, f.x, a2); a3 = fmaf(w, f.y, a3);
        f = __half22float2(*(const __half2*)&hv.z); a4 = fmaf(w, f.x, a4); a5 = fmaf(w, f.y, a5);
        f = __half22float2(*(const __half2*)&hv.w); a6 = fmaf(w, f.x, a6); a7 = fmaf(w, f.y, a7);
    }
    // reduce across the 8 edge slots (lane bits 1..3): xor offsets 2, 4, 8
    #pragma unroll
    for (int off = 2; off <= 8; off <<= 1) {
        a0 += __shfl_xor(a0, off); a1 += __shfl_xor(a1, off);
        a2 += __shfl_xor(a2, off); a3 += __shfl_xor(a3, off);
        a4 += __shfl_xor(a4, off); a5 += __shfl_xor(a5, off);
        a6 += __shfl_xor(a6, off); a7 += __shfl_xor(a7, off);
    }
    if ((lane & 14) == 0) {   // slot == 0 lanes: {nq, part}
        // self term from fp16 (8 feats)
        const uint4 hx = *reinterpret_cast<const uint4*>(xhc + node * 32 + (part << 4));
        float2 f;
        f = __half22float2(*(const __half2*)&hx.x); const float x0f = f.x, x1f = f.y;
        f = __half22float2(*(const __half2*)&hx.y); const float x2f = f.x, x3f = f.y;
        f = __half22float2(*(const __half2*)&hx.z); const float x4f = f.x, x5f = f.y;
        f = __half22float2(*(const __half2*)&hx.w); const float x6f = f.x, x7f = f.y;
        if (node == 0) {   // masked-edge bulk contribution
            const float S0 = *S;
            a0 = fmaf(S0, x0f, a0); a1 = fmaf(S0, x1f, a1);
            a2 = fmaf(S0, x2f, a2); a3 = fmaf(S0, x3f, a3);
            a4 = fmaf(S0, x4f, a4); a5 = fmaf(S0, x5f, a5);
            a6 = fmaf(S0, x6f, a6); a7 = fmaf(S0, x7f, a7);
        }
        const float r0 = fminf(fmaxf(x0f + fminf(fmaxf(a0 - x0f, -1.f), 1.f), 0.f), 2.f);
        const float r1 = fminf(fmaxf(x1f + fminf(fmaxf(a1 - x1f, -1.f), 1.f), 0.f), 2.f);
        const float r2 = fminf(fmaxf(x2f + fminf(fmaxf(a2 - x2f, -1.f), 1.f), 0.f), 2.f);
        const float r3 = fminf(fmaxf(x3f + fminf(fmaxf(a3 - x3f, -1.f), 1.f), 0.f), 2.f);
        const float r4 = fminf(fmaxf(x4f + fminf(fmaxf(a4 - x4f, -1.f), 1.f), 0.f), 2.f);
        const float r5 = fminf(fmaxf(x5f + fminf(fmaxf(a5 - x5f, -1.f), 1.f), 0.f), 2.f);
        const float r6 = fminf(fmaxf(x6f + fminf(fmaxf(a6 - x6f, -1.f), 1.f), 0.f), 2.f);
        const float r7 = fminf(fmaxf(x7f + fminf(fmaxf(a7 - x7f, -1.f), 1.f), 0.f), 2.f);
        __half2 h0 = __floats2half2_rn(r0, r1);
        __half2 h1 = __floats2half2_rn(r2, r3);
        __half2 h2 = __floats2half2_rn(r4, r5);
        __half2 h3 = __floats2half2_rn(r6, r7);
        uint4 hh;
        hh.x = *(unsigned*)&h0; hh.y = *(unsigned*)&h1;
        hh.z = *(unsigned*)&h2; hh.w = *(unsigned*)&h3;
        *reinterpret_cast<uint4*>((char*)outh + (size_t)fh * (NNODES * 32)
                                  + node * 32 + (part << 4)) = hh;
        if (out) {
            float* op = out + node * FEAT + (fh << 4) + (part << 3);
            *reinterpret_cast<float4*>(op)     = make_float4(r0, r1, r2, r3);
            *reinterpret_cast<float4*>(op + 4) = make_float4(r4, r5, r6, r7);
        }
    }
}

extern "C" void kernel_launch(void* const* d_in, const int* in_sizes, int n_in,
                              void* d_out, int out_size, void* d_ws, size_t ws_size,
                              hipStream_t stream) {
    const float* x0         = (const float*)d_in[0];
    const int*   edge_index = (const int*)d_in[1];
    const int*   edge_mask  = (const int*)d_in[2];
    const float* edge_scale = (const float*)d_in[3];
    const float* pert_mask  = (const float*)d_in[4];
    const float* edge_weight= (const float*)d_in[5];
    float* xout = (float*)d_out;

    // ---- workspace layout (time-multiplexed) ----
    // [0, 64K)       S, S_part (782 floats)
    // [64K, 480K)    tb/tboff/bbase/row_ptr
    // [1M, 2.25M)    M
    // [3M, 4.25M)    scanT                       (dead after fill782)
    // [5M, 17.8M)    e8tmp (12.8 MB)             (dead after bsort)
    // [18M, 24.4M)   e4 (6.4 MB)                 (live all gathers)
    // [25M, 50.6M)   pay (25.6 MB)               (dead after fill782)
    //   -> xh0 [25M, 31.4M), xh1 [32M, 38.4M)    (written by cvt/gather, after fill782)
    // [51M, 57.4M)   bkt (6.4 MB)                (dead after fill782)
    char* ws = (char*)d_ws;
    float* S        = (float*)(ws);                          // 4 B
    float* S_part   = (float*)(ws + 1024);                   // 782 floats
    int*   tb       = (int*)(ws + 64 * 1024);                // 299 ints
    int*   tboff    = (int*)(ws + 68 * 1024);                // 299 ints
    int*   bbase    = (int*)(ws + 72 * 1024);                // 392 ints
    int*   row_ptr  = (int*)(ws + 80 * 1024);                // 100001 ints
    int*   M        = (int*)(ws + 1  * 1024 * 1024);         // NT ints (1.22 MB)
    int*   scanT    = (int*)(ws + 3  * 1024 * 1024);         // NT ints (1.22 MB)
    int2*  e8tmp    = (int2*)(ws + 5  * 1024 * 1024);        // ~12.8 MB used
    unsigned* e4    = (unsigned*)(ws + 18 * 1024 * 1024);    // ~6.4 MB used
    int2*  pay      = (int2*)(ws + 25 * 1024 * 1024);        // 25.6 MB
    unsigned short* bkt = (unsigned short*)(ws + 51 * 1024 * 1024);  // 6.4 MB
    __half* xh0     = (__half*)(ws + 25 * 1024 * 1024);      // 6.4 MB, aliases dead pay
    __half* xh1     = (__half*)(ws + 32 * 1024 * 1024);      // 6.4 MB, aliases dead pay

    ws_kernel<<<NBF, 256, 0, stream>>>(edge_index, edge_mask, edge_scale,
                                       pert_mask, edge_weight, pay, bkt, M, S_part);
    sreduce_kernel<<<1, 1024, 0, stream>>>(S_part, S);
    tscan1_kernel<<<NTB, 1024, 0, stream>>>(M, tb);
    tscan2_kernel<<<1, 512, 0, stream>>>(tb, tboff, bbase);
    tscan3_kernel<<<NTB, 1024, 0, stream>>>(M, tboff, scanT, bbase);
    fill782_kernel<<<NBF, 256, 0, stream>>>(pay, bkt, scanT, e8tmp);
    bsort_kernel<<<NBK, 256, 0, stream>>>(e8tmp, bbase, e4, row_ptr);
    cvt_kernel<<<NF / 4 / 256, 256, 0, stream>>>(x0, xh0);   // 3125 blocks, exact

    // 5 gather iterations entirely in fp16 ping-pong; fp32 out written on last iter only
    const int gblocks = 12504;   // 1563*8: both halves, 16 nodes/block, 4 tail blocks idle
    __half* xhb[2] = { xh0, xh1 };
    for (int it = 0; it < NITER; ++it) {
        gather_kernel<<<gblocks, 256, 0, stream>>>(xhb[it & 1], row_ptr, e4, S,
                                                   (it == NITER - 1) ? xout : nullptr,
                                                   xhb[(it + 1) & 1]);
    }
}

// Round 16
// 215.237 us; speedup vs baseline: 1.2696x; 1.0203x over previous
//
#include <hip/hip_runtime.h>
#include <hip/hip_fp16.h>

#define NNODES 100000
#define NEDGES 3200000
#define FEAT 32
#define NITER 5
#define NF (NNODES * FEAT)

// bucket partition
#define BUCK_SH 8
#define BUCK_SZ 256                    // dsts per bucket
#define NBK 391                        // ceil(100000/256)
#define CHUNKF 4096                    // edges per ws/fill block
#define NBF 782                        // 782*4096 = 3,203,072 >= NEDGES
#define NT (NBF * NBK)                 // 305,762 matrix elements
#define NTB 299                        // ceil(NT/1024)

// ---- pass A (fused): packed payload + bucket id + per-block histogram + masked-sum ----
// pay[e] = (src | dstl<<20, w_bits); bkt[e] = dst>>8 (0xFFFF if masked); M[b*NBK+k] = count
__global__ void ws_kernel(const int* __restrict__ edge_index,
                          const int* __restrict__ edge_mask,
                          const float* __restrict__ edge_scale,
                          const float* __restrict__ pert_mask,
                          const float* __restrict__ edge_weight,
                          int2* __restrict__ pay,
                          unsigned short* __restrict__ bkt,
                          int* __restrict__ M,
                          float* __restrict__ S_part) {
    __shared__ int h[NBK];
    __shared__ float sred[256];
    const int b = blockIdx.x;
    for (int k = threadIdx.x; k < NBK; k += 256) h[k] = 0;
    __syncthreads();
    const int base = b * CHUNKF;
    float ms = 0.0f;
    for (int it = 0; it < CHUNKF / 256; ++it) {
        const int e = base + it * 256 + threadIdx.x;
        if (e < NEDGES) {
            const int m = edge_mask[e];
            const float w = (edge_weight[e] * (1.0f - pert_mask[e]) + pert_mask[e]) * edge_scale[e];
            const int src = edge_index[e];
            const int dst = edge_index[NEDGES + e];
            pay[e] = make_int2(src | ((dst & (BUCK_SZ - 1)) << 20), __float_as_int(w));
            if (m) {
                bkt[e] = (unsigned short)(dst >> BUCK_SH);
                atomicAdd(&h[dst >> BUCK_SH], 1);
            } else {
                bkt[e] = (unsigned short)0xFFFFu;
                ms += w;
            }
        }
    }
    sred[threadIdx.x] = ms;
    __syncthreads();                      // also orders all h[] atomics before M write
    for (int off = 128; off; off >>= 1) {
        if (threadIdx.x < off) sred[threadIdx.x] += sred[threadIdx.x + off];
        __syncthreads();
    }
    if (threadIdx.x == 0) S_part[b] = sred[0];
    for (int k = threadIdx.x; k < NBK; k += 256) M[b * NBK + k] = h[k];
}

__global__ void sreduce_kernel(const float* __restrict__ S_part, float* __restrict__ S) {
    __shared__ float s[1024];
    float a = 0.0f;
    for (int i = threadIdx.x; i < NBF; i += 1024) a += S_part[i];
    s[threadIdx.x] = a;
    __syncthreads();
    for (int off = 512; off; off >>= 1) {
        if (threadIdx.x < off) s[threadIdx.x] += s[threadIdx.x + off];
        __syncthreads();
    }
    if (threadIdx.x == 0) *S = s[0];
}

// ---- 3-stage exclusive scan over M in bucket-major (transposed) order ----
__global__ void tscan1_kernel(const int* __restrict__ M, int* __restrict__ tb) {
    __shared__ int s[1024];
    const int i = blockIdx.x * 1024 + threadIdx.x;
    int v = 0;
    if (i < NT) v = M[(i % NBF) * NBK + (i / NBF)];
    s[threadIdx.x] = v;
    __syncthreads();
    for (int off = 512; off; off >>= 1) {
        if (threadIdx.x < off) s[threadIdx.x] += s[threadIdx.x + off];
        __syncthreads();
    }
    if (threadIdx.x == 0) tb[blockIdx.x] = s[0];
}

__global__ void tscan2_kernel(const int* __restrict__ tb, int* __restrict__ tboff,
                              int* __restrict__ bucket_base) {
    __shared__ int s[512];
    const int tid = threadIdx.x;
    int v = (tid < NTB) ? tb[tid] : 0;
    s[tid] = v;
    __syncthreads();
    for (int off = 1; off < 512; off <<= 1) {
        int t = (tid >= off) ? s[tid - off] : 0;
        __syncthreads();
        s[tid] += t;
        __syncthreads();
    }
    if (tid < NTB) tboff[tid] = s[tid] - v;     // exclusive
    if (tid == 511) bucket_base[NBK] = s[511];  // total unmasked edges
}

__global__ void tscan3_kernel(const int* __restrict__ M, const int* __restrict__ tboff,
                              int* __restrict__ scanT, int* __restrict__ bucket_base) {
    __shared__ int s[1024];
    const int tid = threadIdx.x;
    const int i = blockIdx.x * 1024 + tid;
    int v = 0;
    if (i < NT) v = M[(i % NBF) * NBK + (i / NBF)];
    s[tid] = v;
    __syncthreads();
    for (int off = 1; off < 1024; off <<= 1) {
        int t = (tid >= off) ? s[tid - off] : 0;
        __syncthreads();
        s[tid] += t;
        __syncthreads();
    }
    if (i < NT) {
        const int excl = tboff[blockIdx.x] + s[tid] - v;
        scanT[i] = excl;
        if (i % NBF == 0) bucket_base[i / NBF] = excl;
    }
}

// ---- fill: scatter packed payload to matrix offsets; no global atomics ----
__global__ void fill782_kernel(const int2* __restrict__ pay,
                               const unsigned short* __restrict__ bkt,
                               const int* __restrict__ scanT,
                               int2* __restrict__ e8tmp) {
    __shared__ int off[NBK];
    const int b = blockIdx.x;
    for (int k = threadIdx.x; k < NBK; k += 256) off[k] = scanT[k * NBF + b];
    __syncthreads();
    const int base = b * CHUNKF;
    for (int it = 0; it < CHUNKF / 256; ++it) {
        const int e = base + it * 256 + threadIdx.x;
        if (e < NEDGES) {
            const unsigned short k = bkt[e];
            if (k != 0xFFFFu) {
                const int pos = atomicAdd(&off[k], 1);
                e8tmp[pos] = pay[e];
            }
        }
    }
}

// ---- bucket sort: one block per bucket; LDS counting sort by local dst ----
// emits final dst-sorted PACKED e4 (src<<15 | fp16(w) sans sign) and row_ptr.
// w >= 0 always ((ew*(1-pm)+pm)*es, all operands in [0,1)) so the sign bit is free.
__global__ void bsort_kernel(const int2* __restrict__ e8tmp,
                             const int* __restrict__ bucket_base,
                             unsigned* __restrict__ e4,
                             int* __restrict__ row_ptr) {
    __shared__ int h[BUCK_SZ];
    __shared__ int s[BUCK_SZ];
    __shared__ int woff[BUCK_SZ];
    const int k = blockIdx.x;
    const int tid = threadIdx.x;
    const int base0 = bucket_base[k];
    const int cnt = bucket_base[k + 1] - base0;
    h[tid] = 0;
    __syncthreads();
    for (int i = tid; i < cnt; i += 256) {
        const int dstl = e8tmp[base0 + i].x >> 20;   // bits 20..27 (src < 2^17)
        atomicAdd(&h[dstl], 1);
    }
    __syncthreads();
    s[tid] = h[tid];
    __syncthreads();
    for (int off = 1; off < BUCK_SZ; off <<= 1) {
        int t = (tid >= off) ? s[tid - off] : 0;
        __syncthreads();
        s[tid] += t;
        __syncthreads();
    }
    {
        const int excl = s[tid] - h[tid];
        const int d = k * BUCK_SZ + tid;
        if (d < NNODES) row_ptr[d] = base0 + excl;
        woff[tid] = excl;
    }
    if (k == NBK - 1 && tid == 0) row_ptr[NNODES] = bucket_base[NBK];
    __syncthreads();
    for (int i = tid; i < cnt; i += 256) {
        const int2 v = e8tmp[base0 + i];
        const int dstl = v.x >> 20;
        const unsigned src = (unsigned)(v.x & 0xFFFFF);
        __half hw = __float2half_rn(__int_as_float(v.y));
        const unsigned h16 = (unsigned)(*reinterpret_cast<unsigned short*>(&hw)) & 0x7FFFu;
        const int pos = atomicAdd(&woff[dstl], 1);
        e4[base0 + pos] = (src << 15) | h16;
    }
}

// ---- initial fp32 -> fp16 conversion of x0, split-half layout [2][NNODES][16] ----
__global__ void cvt_kernel(const float* __restrict__ x, __half* __restrict__ xh) {
    const int i = blockIdx.x * 256 + threadIdx.x;   // over NF/4
    const float4 v = reinterpret_cast<const float4*>(x)[i];
    const int node = i >> 3;
    const int q = i & 7;           // quarter-row: feats [q*4, q*4+4)
    const int fh = q >> 2;
    const int part = q & 3;
    __half2 h01 = __floats2half2_rn(v.x, v.y);
    __half2 h23 = __floats2half2_rn(v.z, v.w);
    *reinterpret_cast<uint2*>((char*)xh + (size_t)fh * (NNODES * 32) + node * 32 + part * 8)
        = make_uint2(*(unsigned*)&h01, *(unsigned*)&h23);
}

// ---- gather V6: XCD-pinned feature-split, 8 node-halves per wave ----
// bid&7 = XCD: XCDs 0-3 -> feat half 0, 4-7 -> half 1 (per-XCD footprint 3.2 MB < 4 MB L2).
// lane = nq(3) | slot(2) | part(1): 8 nodes x 4 edge slots x 2x16B parts -> 25K waves.
// e4 entry: src<<15 | fp16(w)[14:0]. Byte offset = (v>>10) & ~31.
__global__ void gather_kernel(const __half* __restrict__ xh,
                              const int* __restrict__ row_ptr,
                              const unsigned* __restrict__ e4,
                              const float* __restrict__ S,
                              float* __restrict__ out,       // non-null only on last iter
                              __half* __restrict__ outh) {
    const int bid = blockIdx.x;
    const int r = bid & 7;
    const int fh = r >> 2;                        // feature half
    const int blk = (bid >> 3) * 4 + (r & 3);     // [0, 3128)
    if (blk >= 3125) return;                      // 3125*32 = 100000 exactly
    const int lane = threadIdx.x & 63;
    const int wid = threadIdx.x >> 6;
    const int nq   = lane >> 3;                   // node index in wave 0..7
    const int slot = (lane >> 1) & 3;             // edge slot 0..3
    const int part = lane & 1;                    // 16B part of the 32B half-row
    const int node = blk * 32 + wid * 8 + nq;
    const int beg = row_ptr[node];
    const int end = row_ptr[node + 1];
    const char* xhc = (const char*)xh + (size_t)fh * (NNODES * 32);

    float a0=0.f,a1=0.f,a2=0.f,a3=0.f,a4=0.f,a5=0.f,a6=0.f,a7=0.f;
    const int em1c = (end - 1 > beg) ? (end - 1) : beg;   // safe clamp index
    for (int i = beg + slot; __any(i < end); i += 4) {
        const bool valid = (i < end);
        const unsigned v = e4[valid ? i : em1c];
        unsigned short w16 = (unsigned short)(v & 0x7FFFu);
        const float wv = __half2float(*reinterpret_cast<const __half*>(&w16));
        const float w = valid ? wv : 0.0f;
        const uint4 hv = *reinterpret_cast<const uint4*>(
            xhc + (size_t)((v >> 10) & 0xFFFFE0u) + (part << 4));
        float2 f;
        f = __half22float2(*(const __half2*)&hv.x); a0 = fmaf(w, f.x, a0); a1 = fmaf(w, f.y, a1);
        f = __half22float2(*(const __half2*)&hv.y); a2 = fmaf(w, f.x, a2); a3 = fmaf(w, f.y, a3);
        f = __half22float2(*(const __half2*)&hv.z); a4 = fmaf(w, f.x, a4); a5 = fmaf(w, f.y, a5);
        f = __half22float2(*(const __half2*)&hv.w); a6 = fmaf(w, f.x, a6); a7 = fmaf(w, f.y, a7);
    }
    // reduce across the 4 edge slots (lane bits 1..2): xor offsets 2, 4
    #pragma unroll
    for (int off = 2; off <= 4; off <<= 1) {
        a0 += __shfl_xor(a0, off); a1 += __shfl_xor(a1, off);
        a2 += __shfl_xor(a2, off); a3 += __shfl_xor(a3, off);
        a4 += __shfl_xor(a4, off); a5 += __shfl_xor(a5, off);
        a6 += __shfl_xor(a6, off); a7 += __shfl_xor(a7, off);
    }
    if ((lane & 6) == 0) {   // slot == 0 lanes: {nq, part} (16 lanes)
        // self term from fp16 (8 feats)
        const uint4 hx = *reinterpret_cast<const uint4*>(xhc + node * 32 + (part << 4));
        float2 f;
        f = __half22float2(*(const __half2*)&hx.x); const float x0f = f.x, x1f = f.y;
        f = __half22float2(*(const __half2*)&hx.y); const float x2f = f.x, x3f = f.y;
        f = __half22float2(*(const __half2*)&hx.z); const float x4f = f.x, x5f = f.y;
        f = __half22float2(*(const __half2*)&hx.w); const float x6f = f.x, x7f = f.y;
        if (node == 0) {   // masked-edge bulk contribution
            const float S0 = *S;
            a0 = fmaf(S0, x0f, a0); a1 = fmaf(S0, x1f, a1);
            a2 = fmaf(S0, x2f, a2); a3 = fmaf(S0, x3f, a3);
            a4 = fmaf(S0, x4f, a4); a5 = fmaf(S0, x5f, a5);
            a6 = fmaf(S0, x6f, a6); a7 = fmaf(S0, x7f, a7);
        }
        const float r0 = fminf(fmaxf(x0f + fminf(fmaxf(a0 - x0f, -1.f), 1.f), 0.f), 2.f);
        const float r1 = fminf(fmaxf(x1f + fminf(fmaxf(a1 - x1f, -1.f), 1.f), 0.f), 2.f);
        const float r2 = fminf(fmaxf(x2f + fminf(fmaxf(a2 - x2f, -1.f), 1.f), 0.f), 2.f);
        const float r3 = fminf(fmaxf(x3f + fminf(fmaxf(a3 - x3f, -1.f), 1.f), 0.f), 2.f);
        const float r4 = fminf(fmaxf(x4f + fminf(fmaxf(a4 - x4f, -1.f), 1.f), 0.f), 2.f);
        const float r5 = fminf(fmaxf(x5f + fminf(fmaxf(a5 - x5f, -1.f), 1.f), 0.f), 2.f);
        const float r6 = fminf(fmaxf(x6f + fminf(fmaxf(a6 - x6f, -1.f), 1.f), 0.f), 2.f);
        const float r7 = fminf(fmaxf(x7f + fminf(fmaxf(a7 - x7f, -1.f), 1.f), 0.f), 2.f);
        __half2 h0 = __floats2half2_rn(r0, r1);
        __half2 h1 = __floats2half2_rn(r2, r3);
        __half2 h2 = __floats2half2_rn(r4, r5);
        __half2 h3 = __floats2half2_rn(r6, r7);
        uint4 hh;
        hh.x = *(unsigned*)&h0; hh.y = *(unsigned*)&h1;
        hh.z = *(unsigned*)&h2; hh.w = *(unsigned*)&h3;
        *reinterpret_cast<uint4*>((char*)outh + (size_t)fh * (NNODES * 32)
                                  + node * 32 + (part << 4)) = hh;
        if (out) {
            float* op = out + node * FEAT + (fh << 4) + (part << 3);
            *reinterpret_cast<float4*>(op)     = make_float4(r0, r1, r2, r3);
            *reinterpret_cast<float4*>(op + 4) = make_float4(r4, r5, r6, r7);
        }
    }
}

extern "C" void kernel_launch(void* const* d_in, const int* in_sizes, int n_in,
                              void* d_out, int out_size, void* d_ws, size_t ws_size,
                              hipStream_t stream) {
    const float* x0         = (const float*)d_in[0];
    const int*   edge_index = (const int*)d_in[1];
    const int*   edge_mask  = (const int*)d_in[2];
    const float* edge_scale = (const float*)d_in[3];
    const float* pert_mask  = (const float*)d_in[4];
    const float* edge_weight= (const float*)d_in[5];
    float* xout = (float*)d_out;

    // ---- workspace layout (time-multiplexed) ----
    // [0, 64K)       S, S_part (782 floats)
    // [64K, 480K)    tb/tboff/bbase/row_ptr
    // [1M, 2.25M)    M
    // [3M, 4.25M)    scanT                       (dead after fill782)
    // [5M, 17.8M)    e8tmp (12.8 MB)             (dead after bsort)
    // [18M, 24.4M)   e4 (6.4 MB)                 (live all gathers)
    // [25M, 50.6M)   pay (25.6 MB)               (dead after fill782)
    //   -> xh0 [25M, 31.4M), xh1 [32M, 38.4M)    (written by cvt/gather, after fill782)
    // [51M, 57.4M)   bkt (6.4 MB)                (dead after fill782)
    char* ws = (char*)d_ws;
    float* S        = (float*)(ws);                          // 4 B
    float* S_part   = (float*)(ws + 1024);                   // 782 floats
    int*   tb       = (int*)(ws + 64 * 1024);                // 299 ints
    int*   tboff    = (int*)(ws + 68 * 1024);                // 299 ints
    int*   bbase    = (int*)(ws + 72 * 1024);                // 392 ints
    int*   row_ptr  = (int*)(ws + 80 * 1024);                // 100001 ints
    int*   M        = (int*)(ws + 1  * 1024 * 1024);         // NT ints (1.22 MB)
    int*   scanT    = (int*)(ws + 3  * 1024 * 1024);         // NT ints (1.22 MB)
    int2*  e8tmp    = (int2*)(ws + 5  * 1024 * 1024);        // ~12.8 MB used
    unsigned* e4    = (unsigned*)(ws + 18 * 1024 * 1024);    // ~6.4 MB used
    int2*  pay      = (int2*)(ws + 25 * 1024 * 1024);        // 25.6 MB
    unsigned short* bkt = (unsigned short*)(ws + 51 * 1024 * 1024);  // 6.4 MB
    __half* xh0     = (__half*)(ws + 25 * 1024 * 1024);      // 6.4 MB, aliases dead pay
    __half* xh1     = (__half*)(ws + 32 * 1024 * 1024);      // 6.4 MB, aliases dead pay

    ws_kernel<<<NBF, 256, 0, stream>>>(edge_index, edge_mask, edge_scale,
                                       pert_mask, edge_weight, pay, bkt, M, S_part);
    sreduce_kernel<<<1, 1024, 0, stream>>>(S_part, S);
    tscan1_kernel<<<NTB, 1024, 0, stream>>>(M, tb);
    tscan2_kernel<<<1, 512, 0, stream>>>(tb, tboff, bbase);
    tscan3_kernel<<<NTB, 1024, 0, stream>>>(M, tboff, scanT, bbase);
    fill782_kernel<<<NBF, 256, 0, stream>>>(pay, bkt, scanT, e8tmp);
    bsort_kernel<<<NBK, 256, 0, stream>>>(e8tmp, bbase, e4, row_ptr);
    cvt_kernel<<<NF / 4 / 256, 256, 0, stream>>>(x0, xh0);   // 3125 blocks, exact

    // 5 gather iterations entirely in fp16 ping-pong; fp32 out written on last iter only
    const int gblocks = 6256;   // 782*8: both halves, 32 nodes/block, 3 tail node-blocks idle
    __half* xhb[2] = { xh0, xh1 };
    for (int it = 0; it < NITER; ++it) {
        gather_kernel<<<gblocks, 256, 0, stream>>>(xhb[it & 1], row_ptr, e4, S,
                                                   (it == NITER - 1) ? xout : nullptr,
                                                   xhb[(it + 1) & 1]);
    }
}